// Round 5
// baseline (31953.912 us; speedup 1.0000x reference)
//
#include <hip/hip_runtime.h>
#include <hip/hip_cooperative_groups.h>
#include <stdint.h>

namespace cg = cooperative_groups;

#define BB 4
#define NN 4096
#define DD 64
#define BN (BB*NN)
#define STABF 1e-8f
#define NITER 100
// exp(-cost/eps) = exp2(cost * -1000*log2(e))
#define NEG_SCALE (-1442.695040888963f)

__device__ __forceinline__ float bf16lo(uint32_t w){ return __uint_as_float(w << 16); }
__device__ __forceinline__ float bf16hi(uint32_t w){ return __uint_as_float(w & 0xffff0000u); }
__device__ __forceinline__ uint32_t pack2bf(float f0, float f1){
  uint32_t u0 = __float_as_uint(f0); u0 += 0x7fffu + ((u0 >> 16) & 1u);
  uint32_t u1 = __float_as_uint(f1); u1 += 0x7fffu + ((u1 >> 16) & 1u);
  return (u0 >> 16) | (u1 & 0xffff0000u);
}

// ---------------- init: acc slot0 = N (v0 = 1/(N+stab) ~ 1/N), zero partials
__global__ __launch_bounds__(256) void k_init(float* __restrict__ acc0,
                                              float* __restrict__ partial) {
  int idx = blockIdx.x * 256 + threadIdx.x;   // grid 64 -> 16384 threads
  if (idx < BN) acc0[idx] = (float)NN;
  if (idx < 256) partial[idx] = 0.f;
}

// ---------------- softmax over last dim (64) for both x and y; also sum(p^2)
__global__ __launch_bounds__(256) void k_softmax(
    const float* __restrict__ x, const float* __restrict__ y,
    float* __restrict__ xf, float* __restrict__ yf,
    float* __restrict__ x2, float* __restrict__ y2) {
  int wave = (blockIdx.x * 256 + threadIdx.x) >> 6;   // grid 8192 -> 32768 waves
  int lane = threadIdx.x & 63;
  const float* src; float* dst; float* d2; int row;
  if (wave < BN) { src = x; dst = xf; d2 = x2; row = wave; }
  else           { src = y; dst = yf; d2 = y2; row = wave - BN; }
  float v = src[(size_t)row * DD + lane];
  float m = v;
  #pragma unroll
  for (int off = 32; off; off >>= 1) m = fmaxf(m, __shfl_xor(m, off));
  float e = __expf(v - m);
  float s = e;
  #pragma unroll
  for (int off = 32; off; off >>= 1) s += __shfl_xor(s, off);
  float p = e / s;
  dst[(size_t)row * DD + lane] = p;
  float q = p * p;
  #pragma unroll
  for (int off = 32; off; off >>= 1) q += __shfl_xor(q, off);
  if (lane == 0) d2[row] = q;
}

__device__ __forceinline__ void fma_row(float av0, float av1, const float4 bv,
                                        float cr0[4], float cr1[4]) {
  cr0[0] = fmaf(av0, bv.x, cr0[0]); cr0[1] = fmaf(av0, bv.y, cr0[1]);
  cr0[2] = fmaf(av0, bv.z, cr0[2]); cr0[3] = fmaf(av0, bv.w, cr0[3]);
  cr1[0] = fmaf(av1, bv.x, cr1[0]); cr1[1] = fmaf(av1, bv.y, cr1[1]);
  cr1[2] = fmaf(av1, bv.z, cr1[2]); cr1[3] = fmaf(av1, bv.w, cr1[3]);
}

// ---------------- build K (bf16): tile 32(i) x 64(j), thread micro-tile 2x4
__global__ __launch_bounds__(256) void k_build(
    const float* __restrict__ xf, const float* __restrict__ yf,
    const float* __restrict__ x2, const float* __restrict__ y2,
    unsigned short* __restrict__ K) {
  __shared__ float sxf[32][68];
  __shared__ float syt[64][68];   // transposed: syt[d][j]
  int bid = blockIdx.x, t = threadIdx.x;
  int jt = bid & 63, it = (bid >> 6) & 127, b = bid >> 13;
  int i0 = it * 32, j0 = jt * 64;
  {
    int r = t >> 3, c = (t & 7) * 8;
    const float* s0 = xf + ((size_t)(b*NN + i0 + r)) * DD + c;
    *(float4*)&sxf[r][c]     = *(const float4*)s0;
    *(float4*)&sxf[r][c + 4] = *(const float4*)(s0 + 4);
  }
  {
    int r = t >> 2, c0 = (t & 3) * 16;
    const float* s0 = yf + ((size_t)(b*NN + j0 + r)) * DD + c0;
    #pragma unroll
    for (int q = 0; q < 4; ++q) {
      float4 pv = *(const float4*)(s0 + q*4);
      syt[c0 + q*4 + 0][r] = pv.x;
      syt[c0 + q*4 + 1][r] = pv.y;
      syt[c0 + q*4 + 2][r] = pv.z;
      syt[c0 + q*4 + 3][r] = pv.w;
    }
  }
  __syncthreads();
  int tx = t & 15, ty = t >> 4;
  int ii = ty * 2, jj = tx * 4;
  float cr[2][4] = {{0,0,0,0},{0,0,0,0}};
  #pragma unroll
  for (int d = 0; d < DD; d += 4) {
    float4 a0 = *(const float4*)&sxf[ii][d];
    float4 a1 = *(const float4*)&sxf[ii + 1][d];
    float4 b0 = *(const float4*)&syt[d][jj];
    float4 b1 = *(const float4*)&syt[d + 1][jj];
    float4 b2 = *(const float4*)&syt[d + 2][jj];
    float4 b3 = *(const float4*)&syt[d + 3][jj];
    fma_row(a0.x, a1.x, b0, cr[0], cr[1]);
    fma_row(a0.y, a1.y, b1, cr[0], cr[1]);
    fma_row(a0.z, a1.z, b2, cr[0], cr[1]);
    fma_row(a0.w, a1.w, b3, cr[0], cr[1]);
  }
  float x2v[2], y2v[4];
  x2v[0] = x2[b*NN + i0 + ii]; x2v[1] = x2[b*NN + i0 + ii + 1];
  #pragma unroll
  for (int c = 0; c < 4; ++c) y2v[c] = y2[b*NN + j0 + jj + c];
  #pragma unroll
  for (int i2 = 0; i2 < 2; ++i2) {
    float k4[4];
    #pragma unroll
    for (int c = 0; c < 4; ++c) {
      float cost = fmaxf(x2v[i2] + y2v[c] - 2.f * cr[i2][c], 0.f);
      k4[c] = exp2f(cost * NEG_SCALE);
    }
    uint2 kw;
    kw.x = pack2bf(k4[0], k4[1]);
    kw.y = pack2bf(k4[2], k4[3]);
    *(uint2*)(K + ((size_t)(b*NN + i0 + ii + i2)) * NN + j0 + jj) = kw;
  }
}

// ---------------- persistent cooperative iteration kernel: 100 x (row pass, col pass)
// grid 512 x 256 (2 blocks/CU). All cross-block values communicated inside the
// kernel (u, acc zeroing) go through agent-scope atomics on the VECTOR path:
// block-uniform plain loads would be scalarized into the scalar cache, which
// grid.sync()'s fence does NOT invalidate (buffer_inv only covers vector L1/L2).
__global__ __launch_bounds__(256, 2) void k_iter(
    const unsigned short* __restrict__ K, float* __restrict__ acc0,
    float* __restrict__ acc1, float* __restrict__ u) {
  cg::grid_group grid = cg::this_grid();
  int bid = blockIdx.x, t = threadIdx.x;
  int b = bid >> 7, r = bid & 127;
  int wave = t >> 6, lane = t & 63;
  // row pass geometry: rows [r*32, r*32+32), 8 rows per wave
  int rowbase = r * 32 + wave * 8;
  // col pass geometry: 64-row chunk x 2048-col slab
  int chunk = r >> 1, slab = r & 1;
  int ci0 = chunk * 64, cj0 = slab * 2048 + t * 8;
  const unsigned short* KpB = K + ((size_t)(b*NN + ci0)) * NN + cj0;
  __shared__ float su[64];

  for (int it = 0; it < NITER; ++it) {
    const float* aIn = (it & 1) ? acc1 : acc0;
    float* aOut      = (it & 1) ? acc0 : acc1;
    // zero aOut (my 32-float slice); visible to pass-B atomics after grid.sync
    if (t < 32)
      __hip_atomic_store(&aOut[bid * 32 + t], 0.f, __ATOMIC_RELAXED,
                         __HIP_MEMORY_SCOPE_AGENT);
    // ---- pass A: u[row] = 1/(sum_j K[row][j]*rcp(aIn[j]) + stab)
    {
      const float* ap = aIn + (size_t)b * NN + lane * 8;
      float4 vr[16];
      #pragma unroll
      for (int c = 0; c < 8; ++c) {
        vr[2*c]   = *(const float4*)(ap + c * 512);
        vr[2*c+1] = *(const float4*)(ap + c * 512 + 4);
      }
      #pragma unroll
      for (int c = 0; c < 16; ++c) {
        vr[c].x = __builtin_amdgcn_rcpf(vr[c].x + STABF);
        vr[c].y = __builtin_amdgcn_rcpf(vr[c].y + STABF);
        vr[c].z = __builtin_amdgcn_rcpf(vr[c].z + STABF);
        vr[c].w = __builtin_amdgcn_rcpf(vr[c].w + STABF);
      }
      #pragma unroll
      for (int grp = 0; grp < 2; ++grp) {
        int row0 = rowbase + grp * 4;
        const unsigned short* Kp = K + ((size_t)(b*NN + row0)) * NN + lane * 8;
        float s0 = 0.f, s1 = 0.f, s2 = 0.f, s3 = 0.f;
        #pragma unroll
        for (int c = 0; c < 8; ++c) {
          uint4 k0 = *(const uint4*)(Kp + (size_t)0 * NN + c * 512);
          uint4 k1 = *(const uint4*)(Kp + (size_t)1 * NN + c * 512);
          uint4 k2 = *(const uint4*)(Kp + (size_t)2 * NN + c * 512);
          uint4 k3 = *(const uint4*)(Kp + (size_t)3 * NN + c * 512);
          float4 a0 = vr[2*c], a1 = vr[2*c+1];
          s0 = fmaf(bf16lo(k0.x), a0.x, s0); s0 = fmaf(bf16hi(k0.x), a0.y, s0);
          s0 = fmaf(bf16lo(k0.y), a0.z, s0); s0 = fmaf(bf16hi(k0.y), a0.w, s0);
          s0 = fmaf(bf16lo(k0.z), a1.x, s0); s0 = fmaf(bf16hi(k0.z), a1.y, s0);
          s0 = fmaf(bf16lo(k0.w), a1.z, s0); s0 = fmaf(bf16hi(k0.w), a1.w, s0);
          s1 = fmaf(bf16lo(k1.x), a0.x, s1); s1 = fmaf(bf16hi(k1.x), a0.y, s1);
          s1 = fmaf(bf16lo(k1.y), a0.z, s1); s1 = fmaf(bf16hi(k1.y), a0.w, s1);
          s1 = fmaf(bf16lo(k1.z), a1.x, s1); s1 = fmaf(bf16hi(k1.z), a1.y, s1);
          s1 = fmaf(bf16lo(k1.w), a1.z, s1); s1 = fmaf(bf16hi(k1.w), a1.w, s1);
          s2 = fmaf(bf16lo(k2.x), a0.x, s2); s2 = fmaf(bf16hi(k2.x), a0.y, s2);
          s2 = fmaf(bf16lo(k2.y), a0.z, s2); s2 = fmaf(bf16hi(k2.y), a0.w, s2);
          s2 = fmaf(bf16lo(k2.z), a1.x, s2); s2 = fmaf(bf16hi(k2.z), a1.y, s2);
          s2 = fmaf(bf16lo(k2.w), a1.z, s2); s2 = fmaf(bf16hi(k2.w), a1.w, s2);
          s3 = fmaf(bf16lo(k3.x), a0.x, s3); s3 = fmaf(bf16hi(k3.x), a0.y, s3);
          s3 = fmaf(bf16lo(k3.y), a0.z, s3); s3 = fmaf(bf16hi(k3.y), a0.w, s3);
          s3 = fmaf(bf16lo(k3.z), a1.x, s3); s3 = fmaf(bf16hi(k3.z), a1.y, s3);
          s3 = fmaf(bf16lo(k3.w), a1.z, s3); s3 = fmaf(bf16hi(k3.w), a1.w, s3);
        }
        #pragma unroll
        for (int off = 32; off; off >>= 1) {
          s0 += __shfl_xor(s0, off);
          s1 += __shfl_xor(s1, off);
          s2 += __shfl_xor(s2, off);
          s3 += __shfl_xor(s3, off);
        }
        if (lane == 0) {
          float* up = u + b*NN + row0;
          __hip_atomic_store(up + 0, 1.0f / (s0 + STABF), __ATOMIC_RELAXED, __HIP_MEMORY_SCOPE_AGENT);
          __hip_atomic_store(up + 1, 1.0f / (s1 + STABF), __ATOMIC_RELAXED, __HIP_MEMORY_SCOPE_AGENT);
          __hip_atomic_store(up + 2, 1.0f / (s2 + STABF), __ATOMIC_RELAXED, __HIP_MEMORY_SCOPE_AGENT);
          __hip_atomic_store(up + 3, 1.0f / (s3 + STABF), __ATOMIC_RELAXED, __HIP_MEMORY_SCOPE_AGENT);
        }
      }
    }
    grid.sync();
    // ---- pass B: aOut[j] += sum_i K[i][j] * u[i]  (64-row chunk)
    {
      // stage u chunk into LDS via agent-scope vector loads (never scalar cache)
      if (t < 64)
        su[t] = __hip_atomic_load(&u[b*NN + ci0 + t], __ATOMIC_RELAXED,
                                  __HIP_MEMORY_SCOPE_AGENT);
      __syncthreads();
      float s0=0,s1=0,s2=0,s3=0,s4=0,s5=0,s6=0,s7=0;
      #pragma unroll 4
      for (int rr = 0; rr < 64; ++rr) {
        uint4 kw = *(const uint4*)(KpB + (size_t)rr * NN);
        float ur = su[rr];
        s0 = fmaf(bf16lo(kw.x), ur, s0);
        s1 = fmaf(bf16hi(kw.x), ur, s1);
        s2 = fmaf(bf16lo(kw.y), ur, s2);
        s3 = fmaf(bf16hi(kw.y), ur, s3);
        s4 = fmaf(bf16lo(kw.z), ur, s4);
        s5 = fmaf(bf16hi(kw.z), ur, s5);
        s6 = fmaf(bf16lo(kw.w), ur, s6);
        s7 = fmaf(bf16hi(kw.w), ur, s7);
      }
      float* ap = aOut + b*NN + cj0;
      atomicAdd(ap + 0, s0); atomicAdd(ap + 1, s1);
      atomicAdd(ap + 2, s2); atomicAdd(ap + 3, s3);
      atomicAdd(ap + 4, s4); atomicAdd(ap + 5, s5);
      atomicAdd(ap + 6, s6); atomicAdd(ap + 7, s7);
    }
    grid.sync();
  }
}

// ---------------- fallback (R3) row pass, register-cached v
__global__ __launch_bounds__(256) void k_rowdot(
    const unsigned short* __restrict__ K, const float* __restrict__ accIn,
    float* __restrict__ u, float* __restrict__ accZ) {
  int bid = blockIdx.x, t = threadIdx.x;       // grid 1024: 16 rows/block
  if (bid < 16) {
    float4 z = make_float4(0.f, 0.f, 0.f, 0.f);
    *(float4*)(accZ + (size_t)(bid * 256 + t) * 4) = z;
  }
  int b = bid >> 8, g = bid & 255;
  int wave = t >> 6, lane = t & 63;
  const float* ap = accIn + (size_t)b * NN + lane * 8;
  float4 vr[16];
  #pragma unroll
  for (int c = 0; c < 8; ++c) {
    vr[2*c]   = *(const float4*)(ap + c * 512);
    vr[2*c+1] = *(const float4*)(ap + c * 512 + 4);
  }
  #pragma unroll
  for (int c = 0; c < 16; ++c) {
    vr[c].x = __builtin_amdgcn_rcpf(vr[c].x + STABF);
    vr[c].y = __builtin_amdgcn_rcpf(vr[c].y + STABF);
    vr[c].z = __builtin_amdgcn_rcpf(vr[c].z + STABF);
    vr[c].w = __builtin_amdgcn_rcpf(vr[c].w + STABF);
  }
  int row0 = g * 16 + wave * 4;
  const unsigned short* Kp = K + ((size_t)(b*NN + row0)) * NN + lane * 8;
  float s0 = 0.f, s1 = 0.f, s2 = 0.f, s3 = 0.f;
  #pragma unroll
  for (int c = 0; c < 8; ++c) {
    uint4 k0 = *(const uint4*)(Kp + (size_t)0 * NN + c * 512);
    uint4 k1 = *(const uint4*)(Kp + (size_t)1 * NN + c * 512);
    uint4 k2 = *(const uint4*)(Kp + (size_t)2 * NN + c * 512);
    uint4 k3 = *(const uint4*)(Kp + (size_t)3 * NN + c * 512);
    float4 a0 = vr[2*c], a1 = vr[2*c+1];
    s0 = fmaf(bf16lo(k0.x), a0.x, s0); s0 = fmaf(bf16hi(k0.x), a0.y, s0);
    s0 = fmaf(bf16lo(k0.y), a0.z, s0); s0 = fmaf(bf16hi(k0.y), a0.w, s0);
    s0 = fmaf(bf16lo(k0.z), a1.x, s0); s0 = fmaf(bf16hi(k0.z), a1.y, s0);
    s0 = fmaf(bf16lo(k0.w), a1.z, s0); s0 = fmaf(bf16hi(k0.w), a1.w, s0);
    s1 = fmaf(bf16lo(k1.x), a0.x, s1); s1 = fmaf(bf16hi(k1.x), a0.y, s1);
    s1 = fmaf(bf16lo(k1.y), a0.z, s1); s1 = fmaf(bf16hi(k1.y), a0.w, s1);
    s1 = fmaf(bf16lo(k1.z), a1.x, s1); s1 = fmaf(bf16hi(k1.z), a1.y, s1);
    s1 = fmaf(bf16lo(k1.w), a1.z, s1); s1 = fmaf(bf16hi(k1.w), a1.w, s1);
    s2 = fmaf(bf16lo(k2.x), a0.x, s2); s2 = fmaf(bf16hi(k2.x), a0.y, s2);
    s2 = fmaf(bf16lo(k2.y), a0.z, s2); s2 = fmaf(bf16hi(k2.y), a0.w, s2);
    s2 = fmaf(bf16lo(k2.z), a1.x, s2); s2 = fmaf(bf16hi(k2.z), a1.y, s2);
    s2 = fmaf(bf16lo(k2.w), a1.z, s2); s2 = fmaf(bf16hi(k2.w), a1.w, s2);
    s3 = fmaf(bf16lo(k3.x), a0.x, s3); s3 = fmaf(bf16hi(k3.x), a0.y, s3);
    s3 = fmaf(bf16lo(k3.y), a0.z, s3); s3 = fmaf(bf16hi(k3.y), a0.w, s3);
    s3 = fmaf(bf16lo(k3.z), a1.x, s3); s3 = fmaf(bf16hi(k3.z), a1.y, s3);
    s3 = fmaf(bf16lo(k3.w), a1.z, s3); s3 = fmaf(bf16hi(k3.w), a1.w, s3);
  }
  #pragma unroll
  for (int off = 32; off; off >>= 1) {
    s0 += __shfl_xor(s0, off);
    s1 += __shfl_xor(s1, off);
    s2 += __shfl_xor(s2, off);
    s3 += __shfl_xor(s3, off);
  }
  if (lane == 0) {
    float* up = u + b*NN + row0;
    up[0] = 1.0f / (s0 + STABF);
    up[1] = 1.0f / (s1 + STABF);
    up[2] = 1.0f / (s2 + STABF);
    up[3] = 1.0f / (s3 + STABF);
  }
}

// ---------------- fallback (R3) column pass
__global__ __launch_bounds__(256) void k_coldot(
    const unsigned short* __restrict__ K, const float* __restrict__ u,
    float* __restrict__ acc) {
  int bid = blockIdx.x, t = threadIdx.x;  // grid 512
  int slab = bid & 1, chunk = (bid >> 1) & 63, b = bid >> 7;
  int i0 = chunk * 64;
  int j0 = slab * 2048 + t * 8;
  const unsigned short* Kp = K + ((size_t)(b*NN + i0)) * NN + j0;
  const float* up = u + b*NN + i0;
  float s0=0,s1=0,s2=0,s3=0,s4=0,s5=0,s6=0,s7=0;
  #pragma unroll 4
  for (int r = 0; r < 64; ++r) {
    uint4 kw = *(const uint4*)(Kp + (size_t)r * NN);
    float ur = up[r];
    s0 = fmaf(bf16lo(kw.x), ur, s0);
    s1 = fmaf(bf16hi(kw.x), ur, s1);
    s2 = fmaf(bf16lo(kw.y), ur, s2);
    s3 = fmaf(bf16hi(kw.y), ur, s3);
    s4 = fmaf(bf16lo(kw.z), ur, s4);
    s5 = fmaf(bf16hi(kw.z), ur, s5);
    s6 = fmaf(bf16lo(kw.w), ur, s6);
    s7 = fmaf(bf16hi(kw.w), ur, s7);
  }
  float* ap = acc + b*NN + j0;
  atomicAdd(ap + 0, s0); atomicAdd(ap + 1, s1);
  atomicAdd(ap + 2, s2); atomicAdd(ap + 3, s3);
  atomicAdd(ap + 4, s4); atomicAdd(ap + 5, s5);
  atomicAdd(ap + 6, s6); atomicAdd(ap + 7, s7);
}

// ---------------- dist partials: sum u_i K_ij v_j cost_ij (cost recomputed)
__global__ __launch_bounds__(256) void k_final(
    const float* __restrict__ xf, const float* __restrict__ yf,
    const float* __restrict__ x2, const float* __restrict__ y2,
    const unsigned short* __restrict__ K, const float* __restrict__ u,
    const float* __restrict__ accv, float* __restrict__ partial) {
  __shared__ float sxf[32][68];
  __shared__ float syt[64][68];
  __shared__ float red[256];
  int bid = blockIdx.x, t = threadIdx.x;
  int jt = bid & 63, it = (bid >> 6) & 127, b = bid >> 13;
  int i0 = it * 32, j0 = jt * 64;
  {
    int r = t >> 3, c = (t & 7) * 8;
    const float* s0 = xf + ((size_t)(b*NN + i0 + r)) * DD + c;
    *(float4*)&sxf[r][c]     = *(const float4*)s0;
    *(float4*)&sxf[r][c + 4] = *(const float4*)(s0 + 4);
  }
  {
    int r = t >> 2, c0 = (t & 3) * 16;
    const float* s0 = yf + ((size_t)(b*NN + j0 + r)) * DD + c0;
    #pragma unroll
    for (int q = 0; q < 4; ++q) {
      float4 pv = *(const float4*)(s0 + q*4);
      syt[c0 + q*4 + 0][r] = pv.x;
      syt[c0 + q*4 + 1][r] = pv.y;
      syt[c0 + q*4 + 2][r] = pv.z;
      syt[c0 + q*4 + 3][r] = pv.w;
    }
  }
  __syncthreads();
  int tx = t & 15, ty = t >> 4;
  int ii = ty * 2, jj = tx * 4;
  float cr[2][4] = {{0,0,0,0},{0,0,0,0}};
  #pragma unroll
  for (int d = 0; d < DD; d += 4) {
    float4 a0 = *(const float4*)&sxf[ii][d];
    float4 a1 = *(const float4*)&sxf[ii + 1][d];
    float4 b0 = *(const float4*)&syt[d][jj];
    float4 b1 = *(const float4*)&syt[d + 1][jj];
    float4 b2 = *(const float4*)&syt[d + 2][jj];
    float4 b3 = *(const float4*)&syt[d + 3][jj];
    fma_row(a0.x, a1.x, b0, cr[0], cr[1]);
    fma_row(a0.y, a1.y, b1, cr[0], cr[1]);
    fma_row(a0.z, a1.z, b2, cr[0], cr[1]);
    fma_row(a0.w, a1.w, b3, cr[0], cr[1]);
  }
  float x2v[2], y2v[4], uv[2], vv[4];
  x2v[0] = x2[b*NN + i0 + ii]; x2v[1] = x2[b*NN + i0 + ii + 1];
  uv[0]  = u[b*NN + i0 + ii];  uv[1]  = u[b*NN + i0 + ii + 1];
  #pragma unroll
  for (int c = 0; c < 4; ++c) {
    y2v[c] = y2[b*NN + j0 + jj + c];
    vv[c]  = __builtin_amdgcn_rcpf(accv[b*NN + j0 + jj + c] + STABF);
  }
  float s = 0.f;
  #pragma unroll
  for (int i2 = 0; i2 < 2; ++i2) {
    uint2 kw = *(const uint2*)(K + ((size_t)(b*NN + i0 + ii + i2)) * NN + j0 + jj);
    float kk[4] = {bf16lo(kw.x), bf16hi(kw.x), bf16lo(kw.y), bf16hi(kw.y)};
    #pragma unroll
    for (int c = 0; c < 4; ++c) {
      float cost = fmaxf(x2v[i2] + y2v[c] - 2.f * cr[i2][c], 0.f);
      s = fmaf(uv[i2] * kk[c] * vv[c], cost, s);
    }
  }
  red[t] = s;
  __syncthreads();
  #pragma unroll
  for (int off = 128; off; off >>= 1) {
    if (t < off) red[t] += red[t + off];
    __syncthreads();
  }
  if (t == 0) atomicAdd(partial + (bid & 255), red[0]);
}

__global__ __launch_bounds__(256) void k_finalize(const float* __restrict__ partial,
                                                 float* __restrict__ out) {
  __shared__ float red[256];
  int t = threadIdx.x;
  red[t] = partial[t];
  __syncthreads();
  #pragma unroll
  for (int off = 128; off; off >>= 1) {
    if (t < off) red[t] += red[t + off];
    __syncthreads();
  }
  if (t == 0) out[0] = red[0];
}

extern "C" void kernel_launch(void* const* d_in, const int* in_sizes, int n_in,
                              void* d_out, int out_size, void* d_ws, size_t ws_size,
                              hipStream_t stream) {
  const float* x = (const float*)d_in[0];
  const float* y = (const float*)d_in[1];
  float* out = (float*)d_out;

  char* w = (char*)d_ws;
  unsigned short* K = (unsigned short*)w;                 // 134,217,728 B (bf16 [B,N,N])
  float* xf = (float*)(w + (size_t)BN * NN * 2);          // 4 MB
  float* yf = xf + (size_t)BN * DD;                       // 4 MB
  float* x2 = yf + (size_t)BN * DD;                       // 64 KB
  float* y2 = x2 + BN;                                    // 64 KB
  float* uu = y2 + BN;                                    // 64 KB
  float* acc0 = uu + BN;                                  // 64 KB
  float* acc1 = acc0 + BN;                                // 64 KB
  float* partial = acc1 + BN;                             // 1 KB
  (void)in_sizes; (void)n_in; (void)out_size; (void)ws_size;

  k_init<<<64, 256, 0, stream>>>(acc0, partial);
  k_softmax<<<8192, 256, 0, stream>>>(x, y, xf, yf, x2, y2);
  k_build<<<32768, 256, 0, stream>>>(xf, yf, x2, y2, K);

  // persistent cooperative iteration loop: 100 x (row pass, col pass)
  void* args[] = { (void*)&K, (void*)&acc0, (void*)&acc1, (void*)&uu };
  hipError_t rc = hipLaunchCooperativeKernel((void*)k_iter, dim3(512), dim3(256),
                                             args, 0, stream);
  if (rc != hipSuccess) {
    // deterministic fallback: proven two-kernel loop (R3 structure)
    for (int itr = 0; itr < NITER; ++itr) {
      int p = itr & 1;
      float* aIn  = p ? acc1 : acc0;
      float* aOut = p ? acc0 : acc1;
      k_rowdot<<<1024, 256, 0, stream>>>(K, aIn, uu, aOut);
      k_coldot<<<512, 256, 0, stream>>>(K, uu, aOut);
    }
  }
  // after it=99 (odd), final col sums are in acc0
  k_final<<<32768, 256, 0, stream>>>(xf, yf, x2, y2, K, uu, acc0, partial);
  k_finalize<<<1, 256, 0, stream>>>(partial, out);
}

// Round 6
// 10044.959 us; speedup vs baseline: 3.1811x; 3.1811x over previous
//
#include <hip/hip_runtime.h>
#include <stdint.h>

#define BB 4
#define NN 4096
#define DD 64
#define BN (BB*NN)
#define STABF 1e-8f
#define NITER 100
// exp(-cost/eps) = exp2(cost * -1000*log2(e))
#define NEG_SCALE (-1442.695040888963f)

__device__ __forceinline__ float bf16lo(uint32_t w){ return __uint_as_float(w << 16); }
__device__ __forceinline__ float bf16hi(uint32_t w){ return __uint_as_float(w & 0xffff0000u); }
__device__ __forceinline__ uint32_t pack2bf(float f0, float f1){
  uint32_t u0 = __float_as_uint(f0); u0 += 0x7fffu + ((u0 >> 16) & 1u);
  uint32_t u1 = __float_as_uint(f1); u1 += 0x7fffu + ((u1 >> 16) & 1u);
  return (u0 >> 16) | (u1 & 0xffff0000u);
}

// ---------------- init: acc0 = N (v0 = 1/(N+stab) ~ 1/N), acc1 = 0, partial = 0
__global__ __launch_bounds__(256) void k_init(float* __restrict__ acc0,
                                              float* __restrict__ acc1,
                                              float* __restrict__ partial) {
  int idx = blockIdx.x * 256 + threadIdx.x;   // grid 64 -> 16384 threads
  if (idx < BN) { acc0[idx] = (float)NN; acc1[idx] = 0.f; }
  if (idx < 256) partial[idx] = 0.f;
}

// ---------------- softmax over last dim (64) for both x and y; also sum(p^2)
__global__ __launch_bounds__(256) void k_softmax(
    const float* __restrict__ x, const float* __restrict__ y,
    float* __restrict__ xf, float* __restrict__ yf,
    float* __restrict__ x2, float* __restrict__ y2) {
  int wave = (blockIdx.x * 256 + threadIdx.x) >> 6;   // grid 8192 -> 32768 waves
  int lane = threadIdx.x & 63;
  const float* src; float* dst; float* d2; int row;
  if (wave < BN) { src = x; dst = xf; d2 = x2; row = wave; }
  else           { src = y; dst = yf; d2 = y2; row = wave - BN; }
  float v = src[(size_t)row * DD + lane];
  float m = v;
  #pragma unroll
  for (int off = 32; off; off >>= 1) m = fmaxf(m, __shfl_xor(m, off));
  float e = __expf(v - m);
  float s = e;
  #pragma unroll
  for (int off = 32; off; off >>= 1) s += __shfl_xor(s, off);
  float p = e / s;
  dst[(size_t)row * DD + lane] = p;
  float q = p * p;
  #pragma unroll
  for (int off = 32; off; off >>= 1) q += __shfl_xor(q, off);
  if (lane == 0) d2[row] = q;
}

__device__ __forceinline__ void fma_row(float av0, float av1, const float4 bv,
                                        float cr0[4], float cr1[4]) {
  cr0[0] = fmaf(av0, bv.x, cr0[0]); cr0[1] = fmaf(av0, bv.y, cr0[1]);
  cr0[2] = fmaf(av0, bv.z, cr0[2]); cr0[3] = fmaf(av0, bv.w, cr0[3]);
  cr1[0] = fmaf(av1, bv.x, cr1[0]); cr1[1] = fmaf(av1, bv.y, cr1[1]);
  cr1[2] = fmaf(av1, bv.z, cr1[2]); cr1[3] = fmaf(av1, bv.w, cr1[3]);
}

// ---------------- build K (bf16): tile 32(i) x 64(j), thread micro-tile 2x4
__global__ __launch_bounds__(256) void k_build(
    const float* __restrict__ xf, const float* __restrict__ yf,
    const float* __restrict__ x2, const float* __restrict__ y2,
    unsigned short* __restrict__ K) {
  __shared__ float sxf[32][68];
  __shared__ float syt[64][68];   // transposed: syt[d][j]
  int bid = blockIdx.x, t = threadIdx.x;
  int jt = bid & 63, it = (bid >> 6) & 127, b = bid >> 13;
  int i0 = it * 32, j0 = jt * 64;
  {
    int r = t >> 3, c = (t & 7) * 8;
    const float* s0 = xf + ((size_t)(b*NN + i0 + r)) * DD + c;
    *(float4*)&sxf[r][c]     = *(const float4*)s0;
    *(float4*)&sxf[r][c + 4] = *(const float4*)(s0 + 4);
  }
  {
    int r = t >> 2, c0 = (t & 3) * 16;
    const float* s0 = yf + ((size_t)(b*NN + j0 + r)) * DD + c0;
    #pragma unroll
    for (int q = 0; q < 4; ++q) {
      float4 pv = *(const float4*)(s0 + q*4);
      syt[c0 + q*4 + 0][r] = pv.x;
      syt[c0 + q*4 + 1][r] = pv.y;
      syt[c0 + q*4 + 2][r] = pv.z;
      syt[c0 + q*4 + 3][r] = pv.w;
    }
  }
  __syncthreads();
  int tx = t & 15, ty = t >> 4;
  int ii = ty * 2, jj = tx * 4;
  float cr[2][4] = {{0,0,0,0},{0,0,0,0}};
  #pragma unroll
  for (int d = 0; d < DD; d += 4) {
    float4 a0 = *(const float4*)&sxf[ii][d];
    float4 a1 = *(const float4*)&sxf[ii + 1][d];
    float4 b0 = *(const float4*)&syt[d][jj];
    float4 b1 = *(const float4*)&syt[d + 1][jj];
    float4 b2 = *(const float4*)&syt[d + 2][jj];
    float4 b3 = *(const float4*)&syt[d + 3][jj];
    fma_row(a0.x, a1.x, b0, cr[0], cr[1]);
    fma_row(a0.y, a1.y, b1, cr[0], cr[1]);
    fma_row(a0.z, a1.z, b2, cr[0], cr[1]);
    fma_row(a0.w, a1.w, b3, cr[0], cr[1]);
  }
  float x2v[2], y2v[4];
  x2v[0] = x2[b*NN + i0 + ii]; x2v[1] = x2[b*NN + i0 + ii + 1];
  #pragma unroll
  for (int c = 0; c < 4; ++c) y2v[c] = y2[b*NN + j0 + jj + c];
  #pragma unroll
  for (int i2 = 0; i2 < 2; ++i2) {
    float k4[4];
    #pragma unroll
    for (int c = 0; c < 4; ++c) {
      float cost = fmaxf(x2v[i2] + y2v[c] - 2.f * cr[i2][c], 0.f);
      k4[c] = exp2f(cost * NEG_SCALE);
    }
    uint2 kw;
    kw.x = pack2bf(k4[0], k4[1]);
    kw.y = pack2bf(k4[2], k4[3]);
    *(uint2*)(K + ((size_t)(b*NN + i0 + ii + i2)) * NN + j0 + jj) = kw;
  }
}

// ---------------- fused Sinkhorn step: ONE pass over K per iteration.
// Block owns 32 full rows of K (grid 512 = 4 batches x 128 chunks).
// Sweep 1: u[i] = 1/(sum_j K[i][j]*rcp(accIn[j]+stab) + stab) for its rows
//          (register-cached rcp(v), 8 rows/wave) -> LDS + global u.
// Sweep 2: accOut[j] += sum_i K[i][j]*u[i] over the same 32 rows, reversed
//          row order so the tail of sweep 1 is still L2-resident.
// Blocks 0-15 also zero accZero (the buffer the NEXT iteration accumulates
// into). Triple-buffered acc => no buffer is read and zeroed the same launch.
__global__ __launch_bounds__(256, 2) void k_step(
    const unsigned short* __restrict__ K, const float* __restrict__ accIn,
    float* __restrict__ accOut, float* __restrict__ accZero,
    float* __restrict__ u) {
  int bid = blockIdx.x, t = threadIdx.x;
  if (bid < 16) {
    float4 z = make_float4(0.f, 0.f, 0.f, 0.f);
    *(float4*)(accZero + (size_t)(bid * 256 + t) * 4) = z;
  }
  int b = bid >> 7, chunk = bid & 127;
  int i0 = chunk * 32;
  int wave = t >> 6, lane = t & 63;
  __shared__ float su[32];

  // ---- sweep 1: row sums
  {
    const float* ap = accIn + (size_t)b * NN + lane * 8;
    float4 vr[16];
    #pragma unroll
    for (int c = 0; c < 8; ++c) {
      vr[2*c]   = *(const float4*)(ap + c * 512);
      vr[2*c+1] = *(const float4*)(ap + c * 512 + 4);
    }
    #pragma unroll
    for (int c = 0; c < 16; ++c) {
      vr[c].x = __builtin_amdgcn_rcpf(vr[c].x + STABF);
      vr[c].y = __builtin_amdgcn_rcpf(vr[c].y + STABF);
      vr[c].z = __builtin_amdgcn_rcpf(vr[c].z + STABF);
      vr[c].w = __builtin_amdgcn_rcpf(vr[c].w + STABF);
    }
    #pragma unroll
    for (int grp = 0; grp < 2; ++grp) {
      int lrow = wave * 8 + grp * 4;
      int row0 = i0 + lrow;
      const unsigned short* Kp = K + ((size_t)(b*NN + row0)) * NN + lane * 8;
      float s0 = 0.f, s1 = 0.f, s2 = 0.f, s3 = 0.f;
      #pragma unroll
      for (int c = 0; c < 8; ++c) {
        uint4 k0 = *(const uint4*)(Kp + (size_t)0 * NN + c * 512);
        uint4 k1 = *(const uint4*)(Kp + (size_t)1 * NN + c * 512);
        uint4 k2 = *(const uint4*)(Kp + (size_t)2 * NN + c * 512);
        uint4 k3 = *(const uint4*)(Kp + (size_t)3 * NN + c * 512);
        float4 a0 = vr[2*c], a1 = vr[2*c+1];
        s0 = fmaf(bf16lo(k0.x), a0.x, s0); s0 = fmaf(bf16hi(k0.x), a0.y, s0);
        s0 = fmaf(bf16lo(k0.y), a0.z, s0); s0 = fmaf(bf16hi(k0.y), a0.w, s0);
        s0 = fmaf(bf16lo(k0.z), a1.x, s0); s0 = fmaf(bf16hi(k0.z), a1.y, s0);
        s0 = fmaf(bf16lo(k0.w), a1.z, s0); s0 = fmaf(bf16hi(k0.w), a1.w, s0);
        s1 = fmaf(bf16lo(k1.x), a0.x, s1); s1 = fmaf(bf16hi(k1.x), a0.y, s1);
        s1 = fmaf(bf16lo(k1.y), a0.z, s1); s1 = fmaf(bf16hi(k1.y), a0.w, s1);
        s1 = fmaf(bf16lo(k1.z), a1.x, s1); s1 = fmaf(bf16hi(k1.z), a1.y, s1);
        s1 = fmaf(bf16lo(k1.w), a1.z, s1); s1 = fmaf(bf16hi(k1.w), a1.w, s1);
        s2 = fmaf(bf16lo(k2.x), a0.x, s2); s2 = fmaf(bf16hi(k2.x), a0.y, s2);
        s2 = fmaf(bf16lo(k2.y), a0.z, s2); s2 = fmaf(bf16hi(k2.y), a0.w, s2);
        s2 = fmaf(bf16lo(k2.z), a1.x, s2); s2 = fmaf(bf16hi(k2.z), a1.y, s2);
        s2 = fmaf(bf16lo(k2.w), a1.z, s2); s2 = fmaf(bf16hi(k2.w), a1.w, s2);
        s3 = fmaf(bf16lo(k3.x), a0.x, s3); s3 = fmaf(bf16hi(k3.x), a0.y, s3);
        s3 = fmaf(bf16lo(k3.y), a0.z, s3); s3 = fmaf(bf16hi(k3.y), a0.w, s3);
        s3 = fmaf(bf16lo(k3.z), a1.x, s3); s3 = fmaf(bf16hi(k3.z), a1.y, s3);
        s3 = fmaf(bf16lo(k3.w), a1.z, s3); s3 = fmaf(bf16hi(k3.w), a1.w, s3);
      }
      #pragma unroll
      for (int off = 32; off; off >>= 1) {
        s0 += __shfl_xor(s0, off);
        s1 += __shfl_xor(s1, off);
        s2 += __shfl_xor(s2, off);
        s3 += __shfl_xor(s3, off);
      }
      if (lane == 0) {
        float u0 = 1.0f / (s0 + STABF);
        float u1 = 1.0f / (s1 + STABF);
        float u2 = 1.0f / (s2 + STABF);
        float u3 = 1.0f / (s3 + STABF);
        su[lrow + 0] = u0; su[lrow + 1] = u1;
        su[lrow + 2] = u2; su[lrow + 3] = u3;
        float* up = u + b*NN + row0;
        up[0] = u0; up[1] = u1; up[2] = u2; up[3] = u3;
      }
    }
  }
  __syncthreads();
  // ---- sweep 2: column contributions from the same 32 rows (reversed)
  {
    int c0 = t * 8, c1 = 2048 + t * 8;
    const unsigned short* Kp = K + ((size_t)(b*NN + i0)) * NN;
    float s0=0,s1=0,s2=0,s3=0,s4=0,s5=0,s6=0,s7=0;
    float q0=0,q1=0,q2=0,q3=0,q4=0,q5=0,q6=0,q7=0;
    #pragma unroll 4
    for (int r = 31; r >= 0; --r) {
      const unsigned short* Kr = Kp + (size_t)r * NN;
      uint4 ka = *(const uint4*)(Kr + c0);
      uint4 kb = *(const uint4*)(Kr + c1);
      float ur = su[r];
      s0 = fmaf(bf16lo(ka.x), ur, s0);
      s1 = fmaf(bf16hi(ka.x), ur, s1);
      s2 = fmaf(bf16lo(ka.y), ur, s2);
      s3 = fmaf(bf16hi(ka.y), ur, s3);
      s4 = fmaf(bf16lo(ka.z), ur, s4);
      s5 = fmaf(bf16hi(ka.z), ur, s5);
      s6 = fmaf(bf16lo(ka.w), ur, s6);
      s7 = fmaf(bf16hi(ka.w), ur, s7);
      q0 = fmaf(bf16lo(kb.x), ur, q0);
      q1 = fmaf(bf16hi(kb.x), ur, q1);
      q2 = fmaf(bf16lo(kb.y), ur, q2);
      q3 = fmaf(bf16hi(kb.y), ur, q3);
      q4 = fmaf(bf16lo(kb.z), ur, q4);
      q5 = fmaf(bf16hi(kb.z), ur, q5);
      q6 = fmaf(bf16lo(kb.w), ur, q6);
      q7 = fmaf(bf16hi(kb.w), ur, q7);
    }
    float* a0 = accOut + b*NN + c0;
    atomicAdd(a0 + 0, s0); atomicAdd(a0 + 1, s1);
    atomicAdd(a0 + 2, s2); atomicAdd(a0 + 3, s3);
    atomicAdd(a0 + 4, s4); atomicAdd(a0 + 5, s5);
    atomicAdd(a0 + 6, s6); atomicAdd(a0 + 7, s7);
    float* a1 = accOut + b*NN + c1;
    atomicAdd(a1 + 0, q0); atomicAdd(a1 + 1, q1);
    atomicAdd(a1 + 2, q2); atomicAdd(a1 + 3, q3);
    atomicAdd(a1 + 4, q4); atomicAdd(a1 + 5, q5);
    atomicAdd(a1 + 6, q6); atomicAdd(a1 + 7, q7);
  }
}

// ---------------- dist partials: sum u_i K_ij v_j cost_ij (cost recomputed)
__global__ __launch_bounds__(256) void k_final(
    const float* __restrict__ xf, const float* __restrict__ yf,
    const float* __restrict__ x2, const float* __restrict__ y2,
    const unsigned short* __restrict__ K, const float* __restrict__ u,
    const float* __restrict__ accv, float* __restrict__ partial) {
  __shared__ float sxf[32][68];
  __shared__ float syt[64][68];
  __shared__ float red[256];
  int bid = blockIdx.x, t = threadIdx.x;
  int jt = bid & 63, it = (bid >> 6) & 127, b = bid >> 13;
  int i0 = it * 32, j0 = jt * 64;
  {
    int r = t >> 3, c = (t & 7) * 8;
    const float* s0 = xf + ((size_t)(b*NN + i0 + r)) * DD + c;
    *(float4*)&sxf[r][c]     = *(const float4*)s0;
    *(float4*)&sxf[r][c + 4] = *(const float4*)(s0 + 4);
  }
  {
    int r = t >> 2, c0 = (t & 3) * 16;
    const float* s0 = yf + ((size_t)(b*NN + j0 + r)) * DD + c0;
    #pragma unroll
    for (int q = 0; q < 4; ++q) {
      float4 pv = *(const float4*)(s0 + q*4);
      syt[c0 + q*4 + 0][r] = pv.x;
      syt[c0 + q*4 + 1][r] = pv.y;
      syt[c0 + q*4 + 2][r] = pv.z;
      syt[c0 + q*4 + 3][r] = pv.w;
    }
  }
  __syncthreads();
  int tx = t & 15, ty = t >> 4;
  int ii = ty * 2, jj = tx * 4;
  float cr[2][4] = {{0,0,0,0},{0,0,0,0}};
  #pragma unroll
  for (int d = 0; d < DD; d += 4) {
    float4 a0 = *(const float4*)&sxf[ii][d];
    float4 a1 = *(const float4*)&sxf[ii + 1][d];
    float4 b0 = *(const float4*)&syt[d][jj];
    float4 b1 = *(const float4*)&syt[d + 1][jj];
    float4 b2 = *(const float4*)&syt[d + 2][jj];
    float4 b3 = *(const float4*)&syt[d + 3][jj];
    fma_row(a0.x, a1.x, b0, cr[0], cr[1]);
    fma_row(a0.y, a1.y, b1, cr[0], cr[1]);
    fma_row(a0.z, a1.z, b2, cr[0], cr[1]);
    fma_row(a0.w, a1.w, b3, cr[0], cr[1]);
  }
  float x2v[2], y2v[4], uv[2], vv[4];
  x2v[0] = x2[b*NN + i0 + ii]; x2v[1] = x2[b*NN + i0 + ii + 1];
  uv[0]  = u[b*NN + i0 + ii];  uv[1]  = u[b*NN + i0 + ii + 1];
  #pragma unroll
  for (int c = 0; c < 4; ++c) {
    y2v[c] = y2[b*NN + j0 + jj + c];
    vv[c]  = __builtin_amdgcn_rcpf(accv[b*NN + j0 + jj + c] + STABF);
  }
  float s = 0.f;
  #pragma unroll
  for (int i2 = 0; i2 < 2; ++i2) {
    uint2 kw = *(const uint2*)(K + ((size_t)(b*NN + i0 + ii + i2)) * NN + j0 + jj);
    float kk[4] = {bf16lo(kw.x), bf16hi(kw.x), bf16lo(kw.y), bf16hi(kw.y)};
    #pragma unroll
    for (int c = 0; c < 4; ++c) {
      float cost = fmaxf(x2v[i2] + y2v[c] - 2.f * cr[i2][c], 0.f);
      s = fmaf(uv[i2] * kk[c] * vv[c], cost, s);
    }
  }
  red[t] = s;
  __syncthreads();
  #pragma unroll
  for (int off = 128; off; off >>= 1) {
    if (t < off) red[t] += red[t + off];
    __syncthreads();
  }
  if (t == 0) atomicAdd(partial + (bid & 255), red[0]);
}

__global__ __launch_bounds__(256) void k_finalize(const float* __restrict__ partial,
                                                 float* __restrict__ out) {
  __shared__ float red[256];
  int t = threadIdx.x;
  red[t] = partial[t];
  __syncthreads();
  #pragma unroll
  for (int off = 128; off; off >>= 1) {
    if (t < off) red[t] += red[t + off];
    __syncthreads();
  }
  if (t == 0) out[0] = red[0];
}

extern "C" void kernel_launch(void* const* d_in, const int* in_sizes, int n_in,
                              void* d_out, int out_size, void* d_ws, size_t ws_size,
                              hipStream_t stream) {
  const float* x = (const float*)d_in[0];
  const float* y = (const float*)d_in[1];
  float* out = (float*)d_out;

  char* w = (char*)d_ws;
  unsigned short* K = (unsigned short*)w;                 // 134,217,728 B (bf16 [B,N,N])
  float* xf = (float*)(w + (size_t)BN * NN * 2);          // 4 MB
  float* yf = xf + (size_t)BN * DD;                       // 4 MB
  float* x2 = yf + (size_t)BN * DD;                       // 64 KB
  float* y2 = x2 + BN;                                    // 64 KB
  float* uu = y2 + BN;                                    // 64 KB
  float* acc0 = uu + BN;                                  // 3 x 64 KB (triple buffer)
  float* acc1 = acc0 + BN;
  float* acc2 = acc1 + BN;
  float* partial = acc2 + BN;                             // 1 KB
  (void)in_sizes; (void)n_in; (void)out_size; (void)ws_size;

  k_init<<<64, 256, 0, stream>>>(acc0, acc1, partial);
  k_softmax<<<8192, 256, 0, stream>>>(x, y, xf, yf, x2, y2);
  k_build<<<32768, 256, 0, stream>>>(xf, yf, x2, y2, K);

  float* A[3] = {acc0, acc1, acc2};
  for (int it = 0; it < NITER; ++it) {
    float* aIn   = A[it % 3];
    float* aOut  = A[(it + 1) % 3];
    float* aZero = A[(it + 2) % 3];   // idle this iter; used as aOut next iter
    k_step<<<512, 256, 0, stream>>>(K, aIn, aOut, aZero, uu);
  }
  // after it=99: col sums in A[100 % 3] = A[1]
  k_final<<<32768, 256, 0, stream>>>(xf, yf, x2, y2, K, uu, A[1], partial);
  k_finalize<<<1, 256, 0, stream>>>(partial, out);
}